// Round 3
// baseline (478.156 us; speedup 1.0000x reference)
//
#include <hip/hip_runtime.h>

#define N_BATCH 8
#define I_DIM   32768
#define T_DIM   300
#define O1      410
#define O1P     416               // padded to 104 float4
#define O1Q     104               // float4s per row
#define O2      10
#define KLEN    100
#define NCHUNK  16                // L2-pin chunks of i (2048 rows, 3.4 MB w1t slice)
#define NSUB    64                // list-building segments (512 rows each)
#define SUB_I   (I_DIM / NSUB)    // 512
#define SUBCAP  48                // binomial(512,0.03): mean 15.4, +8.5 sigma
#define SUBPC   (NSUB / NCHUNK)   // 4 sub-lists per chunk
#define NT      (N_BATCH * T_DIM) // 2400
#define GRP     4                 // nt per gather block
#define NTG     (NT / GRP)        // 600

// ---------------- w1 transpose: (410, 32768) -> (32768, 416) zero-padded ----
__global__ void transpose_w1_k(const float* __restrict__ w1, float* __restrict__ w1t) {
    __shared__ float tile[64][65];
    int i0 = blockIdx.x * 64;
    int o0 = blockIdx.y * 64;
    int tx = threadIdx.x & 63;
    int ty = threadIdx.x >> 6;  // 0..3
#pragma unroll
    for (int r = 0; r < 64; r += 4) {
        int o = o0 + r + ty;
        tile[r + ty][tx] = (o < O1) ? w1[(size_t)o * I_DIM + i0 + tx] : 0.0f;
    }
    __syncthreads();
#pragma unroll
    for (int r = 0; r < 64; r += 4) {
        int i = i0 + r + ty;
        int o = o0 + tx;
        if (o < O1P) w1t[(size_t)i * O1P + o] = (o < O1) ? tile[tx][r + ty] : 0.0f;
    }
}

// -------- build active-index lists per (n,t,sub), deterministic ascending-i -
// grid: (N_BATCH, ceil(T/16), NSUB), block: 64 (one wave). 512 rows per block.
__global__ void build_lists_k(const float* __restrict__ x, int* __restrict__ lists,
                              int* __restrict__ counts) {
    int n    = blockIdx.x;
    int t0   = blockIdx.y * 16;
    int seg  = blockIdx.z;
    int lane = threadIdx.x;

    int cnt[16];
#pragma unroll
    for (int tt = 0; tt < 16; tt++) cnt[tt] = 0;

    unsigned long long below = (1ULL << lane) - 1ULL;
    int ibase = seg * SUB_I;

    for (int ii = 0; ii < SUB_I; ii += 64) {
        int i = ibase + ii + lane;
        const float* row = x + ((size_t)(n * I_DIM + i)) * T_DIM + t0;
        float4 q[4];
#pragma unroll
        for (int k = 0; k < 4; k++) {
            if (t0 + 4 * k < T_DIM) q[k] = *reinterpret_cast<const float4*>(row + 4 * k);
            else                    q[k] = make_float4(0.f, 0.f, 0.f, 0.f);
        }
        float vals[16];
#pragma unroll
        for (int k = 0; k < 4; k++) {
            vals[4 * k + 0] = q[k].x; vals[4 * k + 1] = q[k].y;
            vals[4 * k + 2] = q[k].z; vals[4 * k + 3] = q[k].w;
        }
#pragma unroll
        for (int tt = 0; tt < 16; tt++) {
            if (t0 + tt < T_DIM) {
                bool act = (vals[tt] != 0.0f);
                unsigned long long m = __ballot(act);
                if (act) {
                    int pos = cnt[tt] + (int)__popcll(m & below);
                    if (pos < SUBCAP)
                        lists[(size_t)((n * T_DIM + t0 + tt) * NSUB + seg) * SUBCAP + pos] = i;
                }
                cnt[tt] += (int)__popcll(m);
            }
        }
    }
    if (lane == 0) {
#pragma unroll
        for (int tt = 0; tt < 16; tt++) {
            if (t0 + tt < T_DIM) {
                int c = cnt[tt];
                if (c > SUBCAP) c = SUBCAP;
                counts[(n * T_DIM + t0 + tt) * NSUB + seg] = c;
            }
        }
    }
}

__device__ __forceinline__ void add4(float4& a, const float4 b) {
    a.x += b.x; a.y += b.y; a.z += b.z; a.w += b.w;
}

// ------ chunk-pinned sparse gather: partial[nt][chunk][o] over chunk's rows -
// 1-D grid of 2*NTG*8 blocks; b -> (phase, ntg, k), chunk = phase*8+k.
// b%8==k pins chunk k (then k+8) to XCD k so its 3.4 MB w1t slice stays in L2.
// Per chunk, the 4 sub-lists are concatenated in ascending-i order -> same
// summation order as a single per-chunk list.
__global__ __launch_bounds__(512) void gather_partial_k(
        const float4* __restrict__ w1t4, const int* __restrict__ counts,
        const int* __restrict__ lists, float4* __restrict__ partial4) {
    int b     = blockIdx.x;
    int phase = b / (NTG * 8);
    int rem   = b - phase * (NTG * 8);
    int ntg   = rem >> 3;
    int k     = rem & 7;
    int chunk = phase * 8 + k;
    int nt0   = ntg * GRP;
    int tid   = threadIdx.x;

    __shared__ int s_idx[GRP][SUBPC * SUBCAP];   // 4 x 192 ints
    __shared__ int s_off[GRP][SUBPC + 1];

    if (tid < GRP) {
        int off = 0;
#pragma unroll
        for (int s = 0; s < SUBPC; s++) {
            s_off[tid][s] = off;
            off += counts[(nt0 + tid) * NSUB + chunk * SUBPC + s];
        }
        s_off[tid][SUBPC] = off;
    }
    __syncthreads();
    for (int j = tid; j < GRP * SUBPC * SUBCAP; j += 512) {
        int g  = j / (SUBPC * SUBCAP);
        int r  = j - g * (SUBPC * SUBCAP);
        int s  = r / SUBCAP;
        int jj = r - s * SUBCAP;
        int base = s_off[g][s];
        int c    = s_off[g][s + 1] - base;
        if (jj < c)
            s_idx[g][base + jj] =
                lists[(size_t)((nt0 + g) * NSUB + chunk * SUBPC + s) * SUBCAP + jj];
    }
    __syncthreads();

    int g  = tid >> 7;        // 0..3
    int oq = tid & 127;       // 0..127, active < 104
    if (oq < O1Q) {
        const float4* wb = w1t4 + oq;
        int c = s_off[g][SUBPC];
        float4 z4 = make_float4(0.f, 0.f, 0.f, 0.f);
        float4 a0 = z4, a1 = z4, a2 = z4, a3 = z4;
        int j = 0;
        for (; j + 4 <= c; j += 4) {
            add4(a0, wb[(size_t)s_idx[g][j + 0] * O1Q]);
            add4(a1, wb[(size_t)s_idx[g][j + 1] * O1Q]);
            add4(a2, wb[(size_t)s_idx[g][j + 2] * O1Q]);
            add4(a3, wb[(size_t)s_idx[g][j + 3] * O1Q]);
        }
        for (; j < c; j++) add4(a0, wb[(size_t)s_idx[g][j] * O1Q]);
        add4(a0, a1); add4(a2, a3); add4(a0, a2);
        partial4[((size_t)(nt0 + g) * NCHUNK + chunk) * O1Q + oq] = a0;
    }
}

// ---- reduce 16 chunk partials -> up1[n][o][t], fixed ascending-chunk order -
__global__ void reduce_k(const float* __restrict__ partial, float* __restrict__ up1) {
    int id = blockIdx.x * 256 + threadIdx.x;
    if (id >= NT * O1P) return;
    int nt = id / O1P;
    int o  = id - nt * O1P;
    float s = 0.0f;
    const float* p = partial + (size_t)nt * NCHUNK * O1P + o;
#pragma unroll
    for (int c = 0; c < NCHUNK; c++) s += p[c * O1P];
    if (o < O1) {
        int n = nt / T_DIM, t = nt - n * T_DIM;
        up1[((size_t)(n * O1 + o)) * T_DIM + t] = s;
    }
}

// ------------- causal FIR with truncated SRM alpha kernel (100 taps) --------
// grid: nrows blocks (row = 300 contiguous floats), block: 320 threads
__global__ void psp_k(const float* __restrict__ z, float* __restrict__ u) {
    __shared__ float row[T_DIM];
    __shared__ float kern[KLEN];
    int r = blockIdx.x;
    int t = threadIdx.x;
    if (t < KLEN) {
        float a = (float)t / 10.0f;       // t/tauSr, f32 like reference
        kern[t] = a * expf(1.0f - a);
    }
    if (t < T_DIM) row[t] = z[(size_t)r * T_DIM + t];
    __syncthreads();
    if (t < T_DIM) {
        float acc = 0.0f;
        int mmax = t < (KLEN - 1) ? t : (KLEN - 1);
        for (int m = 0; m <= mmax; m++) acc += kern[m] * row[t - m];
        u[(size_t)r * T_DIM + t] = acc;
    }
}

// ---- wave-parallel threshold/refractory scan: lane = row, LDS t-tiles ------
// grid: ceil(nrows/64) blocks, block: 64 threads (one wave)
__global__ __launch_bounds__(64) void spike_tiled_k(const float* __restrict__ u,
                                                    float* __restrict__ s, int nrows) {
    __shared__ float lds[64][65];
    int r0 = blockIdx.x * 64;
    int l  = threadIdx.x;
    int tq = l & 15;          // float4 column within tile
    int rb = l >> 4;          // 0..3
    const float A = 0.36787944117144233f;   // exp(-1)
    const float K = -54.365636569180904f;   // -2*10*e
    float p = 0.0f, y = 0.0f;

    for (int t0 = 0; t0 < T_DIM; t0 += 64) {
        int w = T_DIM - t0; if (w > 64) w = 64;   // 64,64,64,64,44
        // coalesced load: rows r0..r0+63, t-tile -> LDS transposed
#pragma unroll
        for (int rep = 0; rep < 16; rep++) {
            int rr  = rep * 4 + rb;
            int row = r0 + rr;
            if (tq * 4 < w && row < nrows) {
                float4 v = *reinterpret_cast<const float4*>(
                    &u[(size_t)row * T_DIM + t0 + tq * 4]);
                lds[tq * 4 + 0][rr] = v.x; lds[tq * 4 + 1][rr] = v.y;
                lds[tq * 4 + 2][rr] = v.z; lds[tq * 4 + 3][rr] = v.w;
            }
        }
        __syncthreads();
        // serial-in-t scan, one row per lane, exact reference recurrence
        for (int tt = 0; tt < w; tt++) {
            float uv = lds[tt][l];
            y = A * (y + K * p);
            float sp = (uv + y >= 10.0f) ? 1.0f : 0.0f;
            p = A * p + sp;
            lds[tt][l] = sp;
        }
        __syncthreads();
        // coalesced store back
#pragma unroll
        for (int rep = 0; rep < 16; rep++) {
            int rr  = rep * 4 + rb;
            int row = r0 + rr;
            if (tq * 4 < w && row < nrows) {
                float4 v;
                v.x = lds[tq * 4 + 0][rr]; v.y = lds[tq * 4 + 1][rr];
                v.z = lds[tq * 4 + 2][rr]; v.w = lds[tq * 4 + 3][rr];
                *reinterpret_cast<float4*>(&s[(size_t)row * T_DIM + t0 + tq * 4]) = v;
            }
        }
        __syncthreads();
    }
}

// ---------------- dense tiny GEMM2: (8,410,300) x (10,410) ------------------
__global__ void gemm2_k(const float* __restrict__ s1, const float* __restrict__ w2,
                        float* __restrict__ up2) {
    int id = blockIdx.x * 256 + threadIdx.x;
    if (id >= N_BATCH * O2 * T_DIM) return;
    int t  = id % T_DIM;
    int o2 = (id / T_DIM) % O2;
    int n  = id / (T_DIM * O2);
    const float* s1n = s1 + (size_t)n * O1 * T_DIM + t;
    const float* w2r = w2 + o2 * O1;
    float a0 = 0, a1 = 0;
    for (int o = 0; o + 2 <= O1; o += 2) {
        a0 += w2r[o]     * s1n[(size_t)o * T_DIM];
        a1 += w2r[o + 1] * s1n[(size_t)(o + 1) * T_DIM];
    }
    up2[id] = a0 + a1;   // layout (n,o2,t)
}

extern "C" void kernel_launch(void* const* d_in, const int* in_sizes, int n_in,
                              void* d_out, int out_size, void* d_ws, size_t ws_size,
                              hipStream_t stream) {
    const float* x  = (const float*)d_in[0];
    const float* w1 = (const float*)d_in[1];
    const float* w2 = (const float*)d_in[2];
    float* out = (float*)d_out;

    char* ws = (char*)d_ws;
    float* w1t    = (float*)ws;  ws += (size_t)I_DIM * O1P * 4;            // 54.5 MB
    int*   counts = (int*)ws;    ws += (size_t)NT * NSUB * 4;              // 614 KB
    int*   lists  = (int*)ws;    ws += (size_t)NT * NSUB * SUBCAP * 4;     // 29.5 MB
    float* partial= (float*)ws;  ws += (size_t)NT * NCHUNK * O1P * 4;      // 63.9 MB
    float* up1    = (float*)ws;  ws += (size_t)N_BATCH * O1 * T_DIM * 4;   // 3.9 MB
    float* u1     = (float*)ws;  ws += (size_t)N_BATCH * O1 * T_DIM * 4;   // 3.9 MB
    float* s1     = (float*)ws;  ws += (size_t)N_BATCH * O1 * T_DIM * 4;   // 3.9 MB
    float* up2    = (float*)ws;  ws += (size_t)N_BATCH * O2 * T_DIM * 4;   // 96 KB
    float* u2     = (float*)ws;                                            // 96 KB

    transpose_w1_k<<<dim3(I_DIM / 64, (O1P + 63) / 64), 256, 0, stream>>>(w1, w1t);
    build_lists_k<<<dim3(N_BATCH, (T_DIM + 15) / 16, NSUB), 64, 0, stream>>>(x, lists, counts);
    gather_partial_k<<<2 * NTG * 8, 512, 0, stream>>>((const float4*)w1t, counts, lists,
                                                      (float4*)partial);
    reduce_k<<<(NT * O1P + 255) / 256, 256, 0, stream>>>(partial, up1);
    psp_k<<<N_BATCH * O1, 320, 0, stream>>>(up1, u1);
    spike_tiled_k<<<(N_BATCH * O1 + 63) / 64, 64, 0, stream>>>(u1, s1, N_BATCH * O1);
    gemm2_k<<<(N_BATCH * O2 * T_DIM + 255) / 256, 256, 0, stream>>>(s1, w2, up2);
    psp_k<<<N_BATCH * O2, 320, 0, stream>>>(up2, u2);
    spike_tiled_k<<<(N_BATCH * O2 + 63) / 64, 64, 0, stream>>>(u2, out, N_BATCH * O2);
}

// Round 4
// 409.078 us; speedup vs baseline: 1.1689x; 1.1689x over previous
//
#include <hip/hip_runtime.h>

#define N_BATCH 8
#define I_DIM   32768
#define T_DIM   300
#define O1      410
#define O1P     416               // padded to 104 float4
#define O1Q     104               // float4s per row
#define O2      10
#define KLEN    100
#define NCHUNK  16                // L2-pin chunks of i (2048 rows, 3.4 MB w1t slice)
#define NWORD   (I_DIM / 32)      // 1024 bitmask words per (n,t)
#define CHCAP   128               // max actives per chunk: binom(2048,0.03) mean 61, +8.6 sigma
#define NT      (N_BATCH * T_DIM) // 2400
#define GRP     4                 // nt per gather block
#define NTG     (NT / GRP)        // 600

// ---------------- w1 transpose: (410, 32768) -> (32768, 416) zero-padded ----
__global__ void transpose_w1_k(const float* __restrict__ w1, float* __restrict__ w1t) {
    __shared__ float tile[64][65];
    int i0 = blockIdx.x * 64;
    int o0 = blockIdx.y * 64;
    int tx = threadIdx.x & 63;
    int ty = threadIdx.x >> 6;  // 0..3
#pragma unroll
    for (int r = 0; r < 64; r += 4) {
        int o = o0 + r + ty;
        tile[r + ty][tx] = (o < O1) ? w1[(size_t)o * I_DIM + i0 + tx] : 0.0f;
    }
    __syncthreads();
#pragma unroll
    for (int r = 0; r < 64; r += 4) {
        int i = i0 + r + ty;
        int o = o0 + tx;
        if (o < O1P) w1t[(size_t)i * O1P + o] = (o < O1) ? tile[tx][r + ty] : 0.0f;
    }
}

// -------- x -> bitmask xb[n][i_word][t]: coalesced staging + wave ballots ---
// grid: (NWORD, N_BATCH), block 256. Tile = 32 rows x 300 t = 38.4 KB contiguous.
__global__ __launch_bounds__(256) void bitmask_k(const float* __restrict__ x,
                                                 unsigned int* __restrict__ xb) {
    __shared__ float4 tile4[32 * 75];
    __shared__ unsigned int wbuf[300];
    int w   = blockIdx.x;
    int n   = blockIdx.y;
    int tid = threadIdx.x;
    const float4* src = (const float4*)(x + ((size_t)(n * I_DIM + w * 32)) * T_DIM);
    for (int q = tid; q < 32 * 75; q += 256) tile4[q] = src[q];
    __syncthreads();
    const float* tile = (const float*)tile4;
    int wv  = tid >> 6;
    int l   = tid & 63;
    int row = l & 31;
    int th  = l >> 5;
    for (int tp = wv; tp < 150; tp += 4) {
        int t = 2 * tp + th;
        float v = tile[row * 300 + t];
        unsigned long long m = __ballot(v != 0.0f);
        if (l == 0) {
            wbuf[2 * tp]     = (unsigned int)m;          // lanes 0..31  = rows, t even
            wbuf[2 * tp + 1] = (unsigned int)(m >> 32);  // lanes 32..63 = rows, t odd
        }
    }
    __syncthreads();
    if (tid < 75) {
        uint4* dst = (uint4*)(xb + ((size_t)n * NWORD + w) * T_DIM);
        dst[tid] = ((const uint4*)wbuf)[tid];
    }
}

__device__ __forceinline__ void add4(float4& a, const float4 b) {
    a.x += b.x; a.y += b.y; a.z += b.z; a.w += b.w;
}

// ------ chunk-pinned sparse gather with in-block bitmask expansion ----------
// 1-D grid of 2*NTG*8 blocks; b -> (phase, ntg, k), chunk = phase*8+k.
// b%8==k pins chunk k (then k+8) to XCD k so its 3.4 MB w1t slice stays in L2.
// Wave 2g expands chunk's 64 words for nt0+g into ascending-i index list
// (popc + shfl_up prefix + ffs) -> identical summation order to list version.
__global__ __launch_bounds__(512) void gather_partial_k(
        const float4* __restrict__ w1t4, const unsigned int* __restrict__ xb,
        float4* __restrict__ partial4) {
    int b     = blockIdx.x;
    int phase = b / (NTG * 8);
    int rem   = b - phase * (NTG * 8);
    int ntg   = rem >> 3;
    int k     = rem & 7;
    int chunk = phase * 8 + k;
    int nt0   = ntg * GRP;
    int tid   = threadIdx.x;
    int wv    = tid >> 6;
    int l     = tid & 63;

    __shared__ int s_idx[GRP][CHCAP];
    __shared__ int s_cnt[GRP];

    if ((wv & 1) == 0) {
        int g  = wv >> 1;
        int nt = nt0 + g;
        int n  = nt / T_DIM, t = nt - n * T_DIM;
        unsigned int word = xb[((size_t)n * NWORD + chunk * 64 + l) * T_DIM + t];
        int c   = __popc(word);
        int pfx = c;
#pragma unroll
        for (int d = 1; d < 64; d <<= 1) {
            int v = __shfl_up(pfx, d);
            if (l >= d) pfx += v;
        }
        pfx -= c;                         // exclusive prefix over lanes
        int base = chunk * 2048 + l * 32;
        while (word) {
            int bit = __ffs(word) - 1;
            if (pfx < CHCAP) s_idx[g][pfx] = base + bit;
            pfx++;
            word &= word - 1;
        }
        if (l == 63) s_cnt[g] = (pfx < CHCAP) ? pfx : CHCAP;
    }
    __syncthreads();

    int g  = tid >> 7;        // 0..3
    int oq = tid & 127;       // 0..127, active < 104
    if (oq < O1Q) {
        const float4* wb = w1t4 + oq;
        int c = s_cnt[g];
        float4 z4 = make_float4(0.f, 0.f, 0.f, 0.f);
        float4 a0 = z4, a1 = z4, a2 = z4, a3 = z4;
        int j = 0;
        for (; j + 4 <= c; j += 4) {
            add4(a0, wb[(size_t)s_idx[g][j + 0] * O1Q]);
            add4(a1, wb[(size_t)s_idx[g][j + 1] * O1Q]);
            add4(a2, wb[(size_t)s_idx[g][j + 2] * O1Q]);
            add4(a3, wb[(size_t)s_idx[g][j + 3] * O1Q]);
        }
        for (; j < c; j++) add4(a0, wb[(size_t)s_idx[g][j] * O1Q]);
        add4(a0, a1); add4(a2, a3); add4(a0, a2);
        partial4[((size_t)(nt0 + g) * NCHUNK + chunk) * O1Q + oq] = a0;
    }
}

// ---- reduce 16 chunk partials -> up1[n][o][t], fixed ascending-chunk order -
__global__ void reduce_k(const float* __restrict__ partial, float* __restrict__ up1) {
    int id = blockIdx.x * 256 + threadIdx.x;
    if (id >= NT * O1P) return;
    int nt = id / O1P;
    int o  = id - nt * O1P;
    float s = 0.0f;
    const float* p = partial + (size_t)nt * NCHUNK * O1P + o;
#pragma unroll
    for (int c = 0; c < NCHUNK; c++) s += p[c * O1P];
    if (o < O1) {
        int n = nt / T_DIM, t = nt - n * T_DIM;
        up1[((size_t)(n * O1 + o)) * T_DIM + t] = s;
    }
}

// ------------- causal FIR with truncated SRM alpha kernel (100 taps) --------
// grid: nrows blocks (row = 300 contiguous floats), block: 320 threads
__global__ void psp_k(const float* __restrict__ z, float* __restrict__ u) {
    __shared__ float row[T_DIM];
    __shared__ float kern[KLEN];
    int r = blockIdx.x;
    int t = threadIdx.x;
    if (t < KLEN) {
        float a = (float)t / 10.0f;       // t/tauSr, f32 like reference
        kern[t] = a * expf(1.0f - a);
    }
    if (t < T_DIM) row[t] = z[(size_t)r * T_DIM + t];
    __syncthreads();
    if (t < T_DIM) {
        float acc = 0.0f;
        int mmax = t < (KLEN - 1) ? t : (KLEN - 1);
        for (int m = 0; m <= mmax; m++) acc += kern[m] * row[t - m];
        u[(size_t)r * T_DIM + t] = acc;
    }
}

// ---- wave-parallel threshold/refractory scan: lane = row, LDS t-tiles ------
// grid: ceil(nrows/64) blocks, block: 64 threads (one wave)
__global__ __launch_bounds__(64) void spike_tiled_k(const float* __restrict__ u,
                                                    float* __restrict__ s, int nrows) {
    __shared__ float lds[64][65];
    int r0 = blockIdx.x * 64;
    int l  = threadIdx.x;
    int tq = l & 15;          // float4 column within tile
    int rb = l >> 4;          // 0..3
    const float A = 0.36787944117144233f;   // exp(-1)
    const float K = -54.365636569180904f;   // -2*10*e
    float p = 0.0f, y = 0.0f;

    for (int t0 = 0; t0 < T_DIM; t0 += 64) {
        int w = T_DIM - t0; if (w > 64) w = 64;   // 64,64,64,64,44
#pragma unroll
        for (int rep = 0; rep < 16; rep++) {
            int rr  = rep * 4 + rb;
            int row = r0 + rr;
            if (tq * 4 < w && row < nrows) {
                float4 v = *reinterpret_cast<const float4*>(
                    &u[(size_t)row * T_DIM + t0 + tq * 4]);
                lds[tq * 4 + 0][rr] = v.x; lds[tq * 4 + 1][rr] = v.y;
                lds[tq * 4 + 2][rr] = v.z; lds[tq * 4 + 3][rr] = v.w;
            }
        }
        __syncthreads();
        for (int tt = 0; tt < w; tt++) {
            float uv = lds[tt][l];
            y = A * (y + K * p);
            float sp = (uv + y >= 10.0f) ? 1.0f : 0.0f;
            p = A * p + sp;
            lds[tt][l] = sp;
        }
        __syncthreads();
#pragma unroll
        for (int rep = 0; rep < 16; rep++) {
            int rr  = rep * 4 + rb;
            int row = r0 + rr;
            if (tq * 4 < w && row < nrows) {
                float4 v;
                v.x = lds[tq * 4 + 0][rr]; v.y = lds[tq * 4 + 1][rr];
                v.z = lds[tq * 4 + 2][rr]; v.w = lds[tq * 4 + 3][rr];
                *reinterpret_cast<float4*>(&s[(size_t)row * T_DIM + t0 + tq * 4]) = v;
            }
        }
        __syncthreads();
    }
}

// ---------------- dense tiny GEMM2: (8,410,300) x (10,410) ------------------
__global__ void gemm2_k(const float* __restrict__ s1, const float* __restrict__ w2,
                        float* __restrict__ up2) {
    int id = blockIdx.x * 256 + threadIdx.x;
    if (id >= N_BATCH * O2 * T_DIM) return;
    int t  = id % T_DIM;
    int o2 = (id / T_DIM) % O2;
    int n  = id / (T_DIM * O2);
    const float* s1n = s1 + (size_t)n * O1 * T_DIM + t;
    const float* w2r = w2 + o2 * O1;
    float a0 = 0, a1 = 0;
    for (int o = 0; o + 2 <= O1; o += 2) {
        a0 += w2r[o]     * s1n[(size_t)o * T_DIM];
        a1 += w2r[o + 1] * s1n[(size_t)(o + 1) * T_DIM];
    }
    up2[id] = a0 + a1;   // layout (n,o2,t)
}

extern "C" void kernel_launch(void* const* d_in, const int* in_sizes, int n_in,
                              void* d_out, int out_size, void* d_ws, size_t ws_size,
                              hipStream_t stream) {
    const float* x  = (const float*)d_in[0];
    const float* w1 = (const float*)d_in[1];
    const float* w2 = (const float*)d_in[2];
    float* out = (float*)d_out;

    char* ws = (char*)d_ws;
    float*        w1t     = (float*)ws;        ws += (size_t)I_DIM * O1P * 4;          // 54.5 MB
    unsigned int* xb      = (unsigned int*)ws; ws += (size_t)N_BATCH * NWORD * T_DIM * 4; // 9.8 MB
    float*        partial = (float*)ws;        ws += (size_t)NT * NCHUNK * O1P * 4;    // 63.9 MB
    float*        up1     = (float*)ws;        ws += (size_t)N_BATCH * O1 * T_DIM * 4; // 3.9 MB
    float*        u1      = (float*)ws;        ws += (size_t)N_BATCH * O1 * T_DIM * 4; // 3.9 MB
    float*        s1      = (float*)ws;        ws += (size_t)N_BATCH * O1 * T_DIM * 4; // 3.9 MB
    float*        up2     = (float*)ws;        ws += (size_t)N_BATCH * O2 * T_DIM * 4; // 96 KB
    float*        u2      = (float*)ws;                                                // 96 KB

    transpose_w1_k<<<dim3(I_DIM / 64, (O1P + 63) / 64), 256, 0, stream>>>(w1, w1t);
    bitmask_k<<<dim3(NWORD, N_BATCH), 256, 0, stream>>>(x, xb);
    gather_partial_k<<<2 * NTG * 8, 512, 0, stream>>>((const float4*)w1t, xb,
                                                      (float4*)partial);
    reduce_k<<<(NT * O1P + 255) / 256, 256, 0, stream>>>(partial, up1);
    psp_k<<<N_BATCH * O1, 320, 0, stream>>>(up1, u1);
    spike_tiled_k<<<(N_BATCH * O1 + 63) / 64, 64, 0, stream>>>(u1, s1, N_BATCH * O1);
    gemm2_k<<<(N_BATCH * O2 * T_DIM + 255) / 256, 256, 0, stream>>>(s1, w2, up2);
    psp_k<<<N_BATCH * O2, 320, 0, stream>>>(up2, u2);
    spike_tiled_k<<<(N_BATCH * O2 + 63) / 64, 64, 0, stream>>>(u2, out, N_BATCH * O2);
}

// Round 6
// 367.005 us; speedup vs baseline: 1.3029x; 1.1146x over previous
//
#include <hip/hip_runtime.h>

#define N_BATCH 8
#define I_DIM   32768
#define T_DIM   300
#define O1      410
#define O1P     416               // padded to 104 float4
#define O1Q     104               // float4s per row
#define O2      10
#define KLEN    100
#define NCHUNK  16                // L2-pin chunks of i (2048 rows, 3.4 MB w1t slice)
#define NWORD   (I_DIM / 32)      // 1024 bitmask words per (n,t)
#define CHCAP   128               // max actives per chunk
#define NT      (N_BATCH * T_DIM) // 2400
#define GRP     4                 // nt per gather block
#define NTG     (NT / GRP)        // 600
#define PSTRIDE 308               // LDS row stride for psp_spike (16B-aligned)

typedef float nfloat4 __attribute__((ext_vector_type(4)));

__device__ __forceinline__ float4 nt_load4(const float4* p) {
    nfloat4 v = __builtin_nontemporal_load(reinterpret_cast<const nfloat4*>(p));
    return make_float4(v.x, v.y, v.z, v.w);
}
__device__ __forceinline__ void nt_store4(float4* p, float4 v) {
    nfloat4 w = {v.x, v.y, v.z, v.w};
    __builtin_nontemporal_store(w, reinterpret_cast<nfloat4*>(p));
}

// ---------------- w1 transpose: (410, 32768) -> (32768, 416) zero-padded ----
__global__ void transpose_w1_k(const float* __restrict__ w1, float* __restrict__ w1t) {
    __shared__ float tile[64][65];
    int i0 = blockIdx.x * 64;
    int o0 = blockIdx.y * 64;
    int tx = threadIdx.x & 63;
    int ty = threadIdx.x >> 6;  // 0..3
#pragma unroll
    for (int r = 0; r < 64; r += 4) {
        int o = o0 + r + ty;
        tile[r + ty][tx] = (o < O1) ? __builtin_nontemporal_load(&w1[(size_t)o * I_DIM + i0 + tx])
                                    : 0.0f;
    }
    __syncthreads();
#pragma unroll
    for (int r = 0; r < 64; r += 4) {
        int i = i0 + r + ty;
        int o = o0 + tx;
        if (o < O1P) w1t[(size_t)i * O1P + o] = (o < O1) ? tile[tx][r + ty] : 0.0f;
    }
}

// -------- x -> bitmask xb[n][i_word][t]: coalesced staging + wave ballots ---
__global__ __launch_bounds__(256) void bitmask_k(const float* __restrict__ x,
                                                 unsigned int* __restrict__ xb) {
    __shared__ float4 tile4[32 * 75];
    __shared__ unsigned int wbuf[300];
    int w   = blockIdx.x;
    int n   = blockIdx.y;
    int tid = threadIdx.x;
    const float4* src = (const float4*)(x + ((size_t)(n * I_DIM + w * 32)) * T_DIM);
    for (int q = tid; q < 32 * 75; q += 256) tile4[q] = nt_load4(&src[q]);
    __syncthreads();
    const float* tile = (const float*)tile4;
    int wv  = tid >> 6;
    int l   = tid & 63;
    int row = l & 31;
    int th  = l >> 5;
    for (int tp = wv; tp < 150; tp += 4) {
        int t = 2 * tp + th;
        float v = tile[row * 300 + t];
        unsigned long long m = __ballot(v != 0.0f);
        if (l == 0) {
            wbuf[2 * tp]     = (unsigned int)m;
            wbuf[2 * tp + 1] = (unsigned int)(m >> 32);
        }
    }
    __syncthreads();
    if (tid < 75) {
        uint4* dst = (uint4*)(xb + ((size_t)n * NWORD + w) * T_DIM);
        dst[tid] = ((const uint4*)wbuf)[tid];
    }
}

__device__ __forceinline__ void add4(float4& a, const float4 b) {
    a.x += b.x; a.y += b.y; a.z += b.z; a.w += b.w;
}

// ------ chunk-pinned sparse gather with in-block bitmask expansion ----------
// partial writes are NONTEMPORAL so they do not evict the pinned w1t slice.
__global__ __launch_bounds__(512) void gather_partial_k(
        const float4* __restrict__ w1t4, const unsigned int* __restrict__ xb,
        float4* __restrict__ partial4) {
    int b     = blockIdx.x;
    int phase = b / (NTG * 8);
    int rem   = b - phase * (NTG * 8);
    int ntg   = rem >> 3;
    int k     = rem & 7;
    int chunk = phase * 8 + k;
    int nt0   = ntg * GRP;
    int tid   = threadIdx.x;
    int wv    = tid >> 6;
    int l     = tid & 63;

    __shared__ int s_idx[GRP][CHCAP];
    __shared__ int s_cnt[GRP];

    if ((wv & 1) == 0) {
        int g  = wv >> 1;
        int nt = nt0 + g;
        int n  = nt / T_DIM, t = nt - n * T_DIM;
        unsigned int word = xb[((size_t)n * NWORD + chunk * 64 + l) * T_DIM + t];
        int c   = __popc(word);
        int pfx = c;
#pragma unroll
        for (int d = 1; d < 64; d <<= 1) {
            int v = __shfl_up(pfx, d);
            if (l >= d) pfx += v;
        }
        pfx -= c;
        int base = chunk * 2048 + l * 32;
        while (word) {
            int bit = __ffs(word) - 1;
            if (pfx < CHCAP) s_idx[g][pfx] = base + bit;
            pfx++;
            word &= word - 1;
        }
        if (l == 63) s_cnt[g] = (pfx < CHCAP) ? pfx : CHCAP;
    }
    __syncthreads();

    int g  = tid >> 7;
    int oq = tid & 127;
    if (oq < O1Q) {
        const float4* wb = w1t4 + oq;
        int c = s_cnt[g];
        float4 z4 = make_float4(0.f, 0.f, 0.f, 0.f);
        float4 a0 = z4, a1 = z4, a2 = z4, a3 = z4;
        int j = 0;
        for (; j + 4 <= c; j += 4) {
            add4(a0, wb[(size_t)s_idx[g][j + 0] * O1Q]);
            add4(a1, wb[(size_t)s_idx[g][j + 1] * O1Q]);
            add4(a2, wb[(size_t)s_idx[g][j + 2] * O1Q]);
            add4(a3, wb[(size_t)s_idx[g][j + 3] * O1Q]);
        }
        for (; j < c; j++) add4(a0, wb[(size_t)s_idx[g][j] * O1Q]);
        add4(a0, a1); add4(a2, a3); add4(a0, a2);
        nt_store4(&partial4[((size_t)(nt0 + g) * NCHUNK + chunk) * O1Q + oq], a0);
    }
}

// ---- reduce 16 chunk partials -> up1[n][t][o] (t-major), coalesced both ----
__global__ void reduce_k(const float* __restrict__ partial, float* __restrict__ up1) {
    int id = blockIdx.x * 256 + threadIdx.x;
    if (id >= NT * O1P) return;
    int nt = id / O1P;
    int o  = id - nt * O1P;
    const float* p = partial + (size_t)nt * NCHUNK * O1P + o;
    float s = 0.0f;
#pragma unroll
    for (int c = 0; c < NCHUNK; c++) s += __builtin_nontemporal_load(p + c * O1P);
    up1[id] = s;   // up1[n][t][o] == linear id: fully coalesced
}

// ---- fused causal FIR (100-tap, sliding window) + threshold/refractory scan
// input up[n][t][OP] (t-major), output s[n][o][t] (o-row-major).
// block: 256 threads, grid (ceil(O/16), N).
__global__ __launch_bounds__(256) void psp_spike_k(const float* __restrict__ up,
                                                   float* __restrict__ s,
                                                   int OP, int O) {
    __shared__ float zrow[16 * PSTRIDE];
    __shared__ float urow[16 * PSTRIDE];
    __shared__ float kern[104];
    int o0  = blockIdx.x * 16;
    int n   = blockIdx.y;
    int tid = threadIdx.x;

    if (tid < 104) {
        float a = (float)tid / 10.0f;
        kern[tid] = (tid < KLEN) ? a * expf(1.0f - a) : 0.0f;
    }
    for (int idx = tid; idx < 16 * T_DIM; idx += 256) {
        int t = idx >> 4, o = idx & 15;
        zrow[o * PSTRIDE + t] = up[((size_t)n * T_DIM + t) * OP + o0 + o];
    }
    __syncthreads();
    // FIR: each task computes 4 consecutive outputs with a sliding register window
    for (int task = tid; task < 16 * 75; task += 256) {
        int o  = task & 15;
        int t0 = (task >> 4) * 4;
        const float* zr = &zrow[o * PSTRIDE];
        float v0 = zr[t0], v1 = zr[t0 + 1], v2 = zr[t0 + 2], v3 = zr[t0 + 3];
        float a0 = 0.f, a1 = 0.f, a2 = 0.f, a3 = 0.f;
        for (int m = 0; m < KLEN; m++) {
            float km = kern[m];
            a0 += km * v0; a1 += km * v1; a2 += km * v2; a3 += km * v3;
            v3 = v2; v2 = v1; v1 = v0;
            int j = t0 - m - 1;
            v0 = (j >= 0) ? zr[j] : 0.0f;
        }
        *reinterpret_cast<float4*>(&urow[o * PSTRIDE + t0]) = make_float4(a0, a1, a2, a3);
    }
    __syncthreads();
    // serial scan: lane o of wave 0 scans row o, float4-batched LDS access
    if (tid < 16) {
        const float A = 0.36787944117144233f;   // exp(-1)
        const float K = -54.365636569180904f;   // -2*10*e
        float p = 0.0f, y = 0.0f;
        float* ur = &urow[tid * PSTRIDE];
        float* sr = &zrow[tid * PSTRIDE];
        for (int t0 = 0; t0 < 296; t0 += 8) {
            float4 ua = *(const float4*)&ur[t0];
            float4 ub = *(const float4*)&ur[t0 + 4];
            float uv[8] = {ua.x, ua.y, ua.z, ua.w, ub.x, ub.y, ub.z, ub.w};
            float sp[8];
#pragma unroll
            for (int q = 0; q < 8; q++) {
                y = A * (y + K * p);
                float v = (uv[q] + y >= 10.0f) ? 1.0f : 0.0f;
                p = A * p + v;
                sp[q] = v;
            }
            *(float4*)&sr[t0]     = make_float4(sp[0], sp[1], sp[2], sp[3]);
            *(float4*)&sr[t0 + 4] = make_float4(sp[4], sp[5], sp[6], sp[7]);
        }
        {   // tail t = 296..299
            float4 ua = *(const float4*)&ur[296];
            float uv[4] = {ua.x, ua.y, ua.z, ua.w};
            float sp[4];
#pragma unroll
            for (int q = 0; q < 4; q++) {
                y = A * (y + K * p);
                float v = (uv[q] + y >= 10.0f) ? 1.0f : 0.0f;
                p = A * p + v;
                sp[q] = v;
            }
            *(float4*)&sr[296] = make_float4(sp[0], sp[1], sp[2], sp[3]);
        }
    }
    __syncthreads();
    for (int task = tid; task < 16 * 75; task += 256) {
        int o = task & 15, q = task >> 4;
        int oo = o0 + o;
        if (oo < O) {
            float4 v = *(const float4*)&zrow[o * PSTRIDE + q * 4];
            *reinterpret_cast<float4*>(&s[((size_t)n * O + oo) * T_DIM + q * 4]) = v;
        }
    }
}

// ------- GEMM2: thread = (n,t), computes all 10 outputs; w2 staged in LDS ---
// writes up2[n][t][16] (t-major, padded 16, zero-filled tail)
__global__ __launch_bounds__(256) void gemm2_k(const float* __restrict__ s1,
                                               const float* __restrict__ w2,
                                               float* __restrict__ up2) {
    __shared__ float w2s[O2 * O1];
    int tid = threadIdx.x;
    int nt  = blockIdx.x * 256 + tid;
    for (int q = tid; q < O2 * O1; q += 256) w2s[q] = w2[q];
    __syncthreads();
    if (nt >= NT) return;
    int n = nt / T_DIM, t = nt - n * T_DIM;
    float acc[O2];
#pragma unroll
    for (int k = 0; k < O2; k++) acc[k] = 0.0f;
    const float* sp = s1 + (size_t)n * O1 * T_DIM + t;
    for (int o = 0; o < O1; o++) {
        float v = sp[(size_t)o * T_DIM];
#pragma unroll
        for (int k = 0; k < O2; k++) acc[k] += w2s[k * O1 + o] * v;
    }
    float4* dst = (float4*)&up2[(size_t)nt * 16];
    dst[0] = make_float4(acc[0], acc[1], acc[2], acc[3]);
    dst[1] = make_float4(acc[4], acc[5], acc[6], acc[7]);
    dst[2] = make_float4(acc[8], acc[9], 0.f, 0.f);
    dst[3] = make_float4(0.f, 0.f, 0.f, 0.f);
}

extern "C" void kernel_launch(void* const* d_in, const int* in_sizes, int n_in,
                              void* d_out, int out_size, void* d_ws, size_t ws_size,
                              hipStream_t stream) {
    const float* x  = (const float*)d_in[0];
    const float* w1 = (const float*)d_in[1];
    const float* w2 = (const float*)d_in[2];
    float* out = (float*)d_out;

    char* ws = (char*)d_ws;
    float*        w1t     = (float*)ws;        ws += (size_t)I_DIM * O1P * 4;             // 54.5 MB
    unsigned int* xb      = (unsigned int*)ws; ws += (size_t)N_BATCH * NWORD * T_DIM * 4; // 9.8 MB
    float*        partial = (float*)ws;        ws += (size_t)NT * NCHUNK * O1P * 4;       // 63.9 MB
    float*        up1     = (float*)ws;        ws += (size_t)NT * O1P * 4;                // 4.0 MB
    float*        s1      = (float*)ws;        ws += (size_t)N_BATCH * O1 * T_DIM * 4;    // 3.9 MB
    float*        up2     = (float*)ws;                                                   // 154 KB

    transpose_w1_k<<<dim3(I_DIM / 64, (O1P + 63) / 64), 256, 0, stream>>>(w1, w1t);
    bitmask_k<<<dim3(NWORD, N_BATCH), 256, 0, stream>>>(x, xb);
    gather_partial_k<<<2 * NTG * 8, 512, 0, stream>>>((const float4*)w1t, xb,
                                                      (float4*)partial);
    reduce_k<<<(NT * O1P + 255) / 256, 256, 0, stream>>>(partial, up1);
    psp_spike_k<<<dim3((O1 + 15) / 16, N_BATCH), 256, 0, stream>>>(up1, s1, O1P, O1);
    gemm2_k<<<(NT + 255) / 256, 256, 0, stream>>>(s1, w2, up2);
    psp_spike_k<<<dim3(1, N_BATCH), 256, 0, stream>>>(up2, out, 16, O2);
}